// Round 8
// baseline (119.970 us; speedup 1.0000x reference)
//
#include <hip/hip_runtime.h>
#include <math.h>

#define NB 7
#define EPS_ 0.02f
#define ITERS1_ 120   // mant/exp phase, transposed (R4 arithmetic, R7 layout)
#define ITERS2_ 80    // multiplicative phase; total 200 == reference count.
// R12/R14: trajectory matching at exactly 200 iterations is mandatory.
// R1: switch@96 FAILED. Switch stays at 120.
// R2 (log-domain, 1 wave): 57.2us. R4 (mant/exp + stale col scale, 1 wave):
// 57.5us, absmax EXACTLY 1.525879e-05. R7 (log-domain transposed, 7 waves):
// 58.4us, absmax EXACTLY 1.525879e-05. All structures converge ~57-58us:
// per-iter cost ~700cy = serial chain of trans latencies + one cross-thread
// reduce; marginal instr cost is ~2cy/instr (R3/R5 deltas), so the overhead
// is dependent latency, not issue.
// THIS ROUND (R8): fuse R4+R7. Transposed mant/exp: thread(lane=row,
// wave=col) holds scalar (v,F). Row step: one LDS b64 round trip (packed
// v,F), in-thread max+ldexp+sum — s in [0.5,14) by construction => no row
// window/ballot/rescue. Col step: R4 stale scale (XcS per wave == per
// column, SGPR), window on wave-reduced ss, rescue = 6-DPP int max.
// ZERO transcendentals in the loop (2 rcp). Per-column independent rescue
// is bit-equivalent to R4's joint rescue (frame-equivalence, held exactly
// in R4/R6). Expected absmax: exactly 1.525879e-05.
#define TINY_ 1e-40f
#define LOG2E_ 1.4426950408889634f
#define LN2_   0.6931471805599453f

__device__ __forceinline__ float exp2_hw(float x) {
#if __has_builtin(__builtin_amdgcn_exp2f)
    return __builtin_amdgcn_exp2f(x);
#else
    return __expf(x * LN2_);
#endif
}
__device__ __forceinline__ float log2_hw(float x) {
#if __has_builtin(__builtin_amdgcn_logf)
    return __builtin_amdgcn_logf(x);
#else
    return __logf(x) * LOG2E_;
#endif
}
__device__ __forceinline__ float rcp_hw(float x) {
#if __has_builtin(__builtin_amdgcn_rcpf)
    return __builtin_amdgcn_rcpf(x);
#else
    return 1.0f / x;
#endif
}
__device__ __forceinline__ float ldexp_hw(float x, int e) {
#if __has_builtin(__builtin_amdgcn_ldexpf)
    return __builtin_amdgcn_ldexpf(x, e);
#else
    float r; asm("v_ldexp_f32 %0, %1, %2" : "=v"(r) : "v"(x), "v"(e)); return r;
#endif
}
__device__ __forceinline__ float frexp_mant_hw(float x) {
#if __has_builtin(__builtin_amdgcn_frexp_mantf)
    return __builtin_amdgcn_frexp_mantf(x);
#else
    float r; asm("v_frexp_mant_f32 %0, %1" : "=v"(r) : "v"(x)); return r;
#endif
}
__device__ __forceinline__ int frexp_exp_hw(float x) {
#if __has_builtin(__builtin_amdgcn_frexp_expf)
    return __builtin_amdgcn_frexp_expf(x);
#else
    int r; asm("v_frexp_exp_i32_f32 %0, %1" : "=v"(r) : "v"(x)); return r;
#endif
}

// ---- DPP helpers ----
template <int CTRL>
__device__ __forceinline__ float dpp_ident(float identity, float x) {
    return __int_as_float(__builtin_amdgcn_update_dpp(
        __float_as_int(identity), __float_as_int(x), CTRL, 0xF, 0xF, false));
}
template <int CTRL>
__device__ __forceinline__ int dpp_ident_i(int identity, int x) {
    return __builtin_amdgcn_update_dpp(identity, x, CTRL, 0xF, 0xF, false);
}
__device__ __forceinline__ float readlane63(float x) {
    return __int_as_float(__builtin_amdgcn_readlane(__float_as_int(x), 63));
}
__device__ __forceinline__ float wave_sum_bcast(float s) {
    s += dpp_ident<0x111>(0.f, s);
    s += dpp_ident<0x112>(0.f, s);
    s += dpp_ident<0x114>(0.f, s);
    s += dpp_ident<0x118>(0.f, s);
    s += dpp_ident<0x142>(0.f, s);
    s += dpp_ident<0x143>(0.f, s);
    return readlane63(s);
}
__device__ __forceinline__ int wave_maxi_bcast(int m) {
    const int NI = (int)0x80000000;
    m = max(m, dpp_ident_i<0x111>(NI, m));
    m = max(m, dpp_ident_i<0x112>(NI, m));
    m = max(m, dpp_ident_i<0x114>(NI, m));
    m = max(m, dpp_ident_i<0x118>(NI, m));
    m = max(m, dpp_ident_i<0x142>(NI, m));
    m = max(m, dpp_ident_i<0x143>(NI, m));
    return __builtin_amdgcn_readlane(m, 63);
}

#define RS_ 9   // float2 row stride: bank spread 16, ~4-way on b64 (benign)

__global__ __launch_bounds__(448) void sinkhorn_kernel(
    const float* __restrict__ theta,  // [64,7]
    const float* __restrict__ phi,    // [7]
    const float* __restrict__ n,      // [64]
    const float* __restrict__ sens,   // [64]
    const float* __restrict__ err,    // [7]
    float* __restrict__ out)          // [64,7]
{
    const int tid  = threadIdx.x;
    const int lane = tid & 63;        // row
    const int wid  = tid >> 6;        // column 0..6 (one wave per column)

    __shared__ float2 buf[2][64 * RS_ + 4];   // (v, F-as-bits) per cell
    __shared__ float  ldsS[8];                // epilogue column sums

    const float ni = n[lane];
    const float si = sens[lane];
    const float ej = err[wid];
    const float th = theta[lane * NB + wid];

    // nsum identical in every wave (same per-lane ni, same tree).
    const float nsum   = wave_sum_bcast(ni);
    const float aT     = ni / nsum + TINY_;
    const float log_a2 = log2_hw(aT);

    // softmax(phi): same scalar sequence as R2/R7.
    float t2v0 = phi[0] * LOG2E_, t2v1 = phi[1] * LOG2E_,
          t2v2 = phi[2] * LOG2E_, t2v3 = phi[3] * LOG2E_,
          t2v4 = phi[4] * LOG2E_, t2v5 = phi[5] * LOG2E_,
          t2v6 = phi[6] * LOG2E_;
    float pmax = t2v0;
    pmax = fmaxf(pmax, t2v1); pmax = fmaxf(pmax, t2v2);
    pmax = fmaxf(pmax, t2v3); pmax = fmaxf(pmax, t2v4);
    pmax = fmaxf(pmax, t2v5); pmax = fmaxf(pmax, t2v6);
    float psum = exp2_hw(t2v0 - pmax);
    psum += exp2_hw(t2v1 - pmax); psum += exp2_hw(t2v2 - pmax);
    psum += exp2_hw(t2v3 - pmax); psum += exp2_hw(t2v4 - pmax);
    psum += exp2_hw(t2v5 - pmax); psum += exp2_hw(t2v6 - pmax);
    const float lps  = log2_hw(psum);
    const float myt2 = phi[wid] * LOG2E_;
    const float bTj  = exp2_hw(myt2 - pmax - lps) + TINY_;
    const float lb2j = log2_hw(bTj);
    const float cbj  = lb2j - log_a2;
    const float b2c  = exp2_hw(cbj);
    const float ibc  = exp2_hw(-cbj);

    // ---- Phase 1 state (R4's init, per-cell scalar): E = v * 2^F ----
    const float kscale = LOG2E_ / EPS_;
    const float y  = (th - ni * si * ej) * kscale - log_a2;   // K2 - log_a2
    const float yi = rintf(y);
    int   F = (int)yi;
    float v = exp2_hw(y - yi);                // in [2^-0.5, 2^0.5]

    int XcS = 0;                              // stale column scale (uniform)
    const float LO80f = __int_as_float(0x17800000);   // 2^-80
    const float HI80f = __int_as_float(0x67800000);   // 2^+80

    const int base = lane * RS_ + wid;
    const int rb   = lane * RS_;

    for (int it = 0; it < ITERS1_; ++it) {
        const int p = it & 1;
        buf[p][base] = make_float2(v, __int_as_float(F));   // ds_write_b64
        __syncthreads();

        // Row step: read 7 (v,F) pairs; exact max-align; sum (R4 tree order).
        const float2 c0 = buf[p][rb + 0], c1 = buf[p][rb + 1],
                     c2 = buf[p][rb + 2], c3 = buf[p][rb + 3],
                     c4 = buf[p][rb + 4], c5 = buf[p][rb + 5],
                     c6 = buf[p][rb + 6];
        const int F0 = __float_as_int(c0.y), F1 = __float_as_int(c1.y),
                  F2 = __float_as_int(c2.y), F3 = __float_as_int(c3.y),
                  F4 = __float_as_int(c4.y), F5 = __float_as_int(c5.y),
                  F6 = __float_as_int(c6.y);
        const int X = max(max(max(F0, F1), max(F2, F3)),
                          max(max(F4, F5), F6));
        const float f0 = ldexp_hw(c0.x, F0 - X), f1 = ldexp_hw(c1.x, F1 - X),
                    f2 = ldexp_hw(c2.x, F2 - X), f3 = ldexp_hw(c3.x, F3 - X),
                    f4 = ldexp_hw(c4.x, F4 - X), f5 = ldexp_hw(c5.x, F5 - X),
                    f6 = ldexp_hw(c6.x, F6 - X);
        const float s  = ((f0 + f1) + (f2 + f3)) + ((f4 + f5) + f6); // [0.5,14)
        const float rs = rcp_hw(s);

        const float w  = (v * ibc) * rs;      // normal by construction
        const int   Fw = F - X;

        // Column step: stale scale + window; rescue = exact wave int-max.
        int d = Fw - XcS;
        float h  = ldexp_hw(w, d);
        float ss = wave_sum_bcast(h);         // wave-uniform
        if (!(ss >= LO80f && ss <= HI80f)) {  // NaN/inf/0 -> rescue
            const int M = wave_maxi_bcast(Fw);
            d  = Fw - M;
            h  = ldexp_hw(w, d);
            ss = wave_sum_bcast(h);
            XcS = M;
        }

        const float z = (w * rcp_hw(ss)) * b2c;   // normal (window-guarded)
        v = frexp_mant_hw(z);
        F = frexp_exp_hw(z) + d;
    }

    // ---- Switch @120 (R4 formula): U = ldexp(v*ibc, F); underflow->0. ----
    float U = ldexp_hw(v * ibc, F);
    const float Bj = b2c;

    // ---- Phase 2: multiplicative, transposed (R7-verbatim). ----
    for (int it2 = 0; it2 < ITERS2_; ++it2) {
        const int p = it2 & 1;
        buf[p][base].x = U * Bj;
        __syncthreads();
        const float p0 = buf[p][rb + 0].x, p1 = buf[p][rb + 1].x,
                    p2 = buf[p][rb + 2].x, p3 = buf[p][rb + 3].x,
                    p4 = buf[p][rb + 4].x, p5 = buf[p][rb + 5].x,
                    p6 = buf[p][rb + 6].x;
        const float s  = ((p0 + p1) + (p2 + p3)) + ((p4 + p5) + p6);
        const float rsv = rcp_hw(s);
        const float w   = U * rsv;
        const float ss  = wave_sum_bcast(w);
        U = w * rcp_hw(ss);
    }

    // ---- Epilogue: P = U*bT; normalize by total (+TINY). ----
    const float pr = U * bTj;
    const float cs = wave_sum_bcast(pr);   // column sum (wave-uniform)
    if (lane == 0) ldsS[wid] = cs;
    __syncthreads();
    const float total = ((ldsS[0] + ldsS[1]) + (ldsS[2] + ldsS[3]))
                      + ((ldsS[4] + ldsS[5]) + ldsS[6]);
    out[lane * NB + wid] = pr * (1.0f / (total + TINY_));
}

extern "C" void kernel_launch(void* const* d_in, const int* in_sizes, int n_in,
                              void* d_out, int out_size, void* d_ws, size_t ws_size,
                              hipStream_t stream) {
    const float* theta = (const float*)d_in[0];
    const float* phi   = (const float*)d_in[1];
    const float* n     = (const float*)d_in[2];
    const float* sens  = (const float*)d_in[3];
    const float* err   = (const float*)d_in[4];
    float* out = (float*)d_out;

    sinkhorn_kernel<<<1, 448, 0, stream>>>(theta, phi, n, sens, err, out);
}

// Round 9
// 110.810 us; speedup vs baseline: 1.0827x; 1.0827x over previous
//
#include <hip/hip_runtime.h>
#include <math.h>

#define NB 7
#define EPS_ 0.02f
#define ITERS1_ 120   // log-domain phase (R2-equivalent logic, transposed)
#define ITERS2_ 80    // multiplicative phase; total 200 == reference count.
// R12/R14: trajectory matching at exactly 200 iterations is mandatory.
// R1: switch@96 FAILED. Switch stays at 120.
// Structure history: R2 (1-wave log) 57.2us; R4 (1-wave mant/exp) 57.5us;
// R7 (7-wave transposed log) 58.4us / BEST bench 111.3; R8 (7-wave mant/exp)
// 61.6us. All converge ~57-62: one cross-wave exchange (LDS RT + barrier)
// + one wave reduce + serial chain per iteration is structural.
// THIS ROUND (R9): R7 with chain-scheduling polish, bit-identical trajectory:
// (a) speculative log2(s)/log2(ss) issued BEFORE the window checks (rescue
//     overwrites) — removes ballot/branch resolution from the critical path;
// (b) column window check as uint compare on the SGPR-resident ss
//     (equivalent for >=0 sums; NaN/inf/0 -> rescue unchanged).
// Expected absmax: exactly 1.525879e-05.
#define TINY_ 1e-40f
#define LOG2E_ 1.4426950408889634f
#define LN2_   0.6931471805599453f

__device__ __forceinline__ float exp2_hw(float x) {
#if __has_builtin(__builtin_amdgcn_exp2f)
    return __builtin_amdgcn_exp2f(x);
#else
    return __expf(x * LN2_);
#endif
}
__device__ __forceinline__ float log2_hw(float x) {
#if __has_builtin(__builtin_amdgcn_logf)
    return __builtin_amdgcn_logf(x);
#else
    return __logf(x) * LOG2E_;
#endif
}
__device__ __forceinline__ float rcp_hw(float x) {
#if __has_builtin(__builtin_amdgcn_rcpf)
    return __builtin_amdgcn_rcpf(x);
#else
    return 1.0f / x;
#endif
}

// ---- DPP helpers (proven in prior rounds) ----
template <int CTRL>
__device__ __forceinline__ float dpp_ident(float identity, float x) {
    return __int_as_float(__builtin_amdgcn_update_dpp(
        __float_as_int(identity), __float_as_int(x), CTRL, 0xF, 0xF, false));
}
__device__ __forceinline__ float readlane63(float x) {
    return __int_as_float(__builtin_amdgcn_readlane(__float_as_int(x), 63));
}
__device__ __forceinline__ float wave_sum_bcast(float s) {
    s += dpp_ident<0x111>(0.f, s);
    s += dpp_ident<0x112>(0.f, s);
    s += dpp_ident<0x114>(0.f, s);
    s += dpp_ident<0x118>(0.f, s);
    s += dpp_ident<0x142>(0.f, s);
    s += dpp_ident<0x143>(0.f, s);
    return readlane63(s);
}
__device__ __forceinline__ float wave_max_bcast(float m) {
    const float NI = __int_as_float(0xff800000);
    m = fmaxf(m, dpp_ident<0x111>(NI, m));
    m = fmaxf(m, dpp_ident<0x112>(NI, m));
    m = fmaxf(m, dpp_ident<0x114>(NI, m));
    m = fmaxf(m, dpp_ident<0x118>(NI, m));
    m = fmaxf(m, dpp_ident<0x142>(NI, m));
    m = fmaxf(m, dpp_ident<0x143>(NI, m));
    return readlane63(m);
}

#define STRIDE_ 9   // 9 coprime 32 -> 2 lanes/bank on row reads/writes (free)

__global__ __launch_bounds__(448) void sinkhorn_kernel(
    const float* __restrict__ theta,  // [64,7]
    const float* __restrict__ phi,    // [7]
    const float* __restrict__ n,      // [64]
    const float* __restrict__ sens,   // [64]
    const float* __restrict__ err,    // [7]
    float* __restrict__ out)          // [64,7]
{
    const int tid  = threadIdx.x;
    const int lane = tid & 63;        // row
    const int wid  = tid >> 6;        // column 0..6 (one wave per column)

    __shared__ float bufEA[2][64 * STRIDE_ + 8];   // exp2(a) per cell
    __shared__ float bufAA[2][64 * STRIDE_ + 8];   // a per cell (rescue)
    __shared__ float ldsS[8];                      // epilogue column sums

    const float ni = n[lane];
    const float si = sens[lane];
    const float ej = err[wid];
    const float th = theta[lane * NB + wid];

    // nsum identical in every wave (same per-lane ni, same tree).
    const float nsum   = wave_sum_bcast(ni);
    const float aT     = ni / nsum + TINY_;
    const float log_a2 = log2_hw(aT);

    // softmax(phi): same scalar sequence as R2/R7.
    float t2v0 = phi[0] * LOG2E_, t2v1 = phi[1] * LOG2E_,
          t2v2 = phi[2] * LOG2E_, t2v3 = phi[3] * LOG2E_,
          t2v4 = phi[4] * LOG2E_, t2v5 = phi[5] * LOG2E_,
          t2v6 = phi[6] * LOG2E_;
    float pmax = t2v0;
    pmax = fmaxf(pmax, t2v1); pmax = fmaxf(pmax, t2v2);
    pmax = fmaxf(pmax, t2v3); pmax = fmaxf(pmax, t2v4);
    pmax = fmaxf(pmax, t2v5); pmax = fmaxf(pmax, t2v6);
    float psum = exp2_hw(t2v0 - pmax);
    psum += exp2_hw(t2v1 - pmax); psum += exp2_hw(t2v2 - pmax);
    psum += exp2_hw(t2v3 - pmax); psum += exp2_hw(t2v4 - pmax);
    psum += exp2_hw(t2v5 - pmax); psum += exp2_hw(t2v6 - pmax);
    const float lps  = log2_hw(psum);
    const float myt2 = phi[wid] * LOG2E_;
    const float bTj  = exp2_hw(myt2 - pmax - lps) + TINY_;
    const float lb2j = log2_hw(bTj);
    const float cbj  = lb2j - log_a2;

    const float kscale = LOG2E_ / EPS_;
    float t = (th - ni * si * ej) * kscale - lb2j;

    const float LOF = __int_as_float(0x0D800000);  // 2^-100
    const float HIF = __int_as_float(0x71800000);  // 2^+100
    const unsigned LOu = 0x0D800000u, HIu = 0x71800000u;
    const int   base = lane * STRIDE_ + wid;
    const int   rb   = lane * STRIDE_;

    // ---- Phase 1: log-domain, transposed. 1 barrier/iter (parity dbuf). ----
    for (int it = 0; it < ITERS1_; ++it) {
        const int p = it & 1;
        const float a = t + cbj;
        bufEA[p][base] = exp2_hw(a);
        bufAA[p][base] = a;
        __syncthreads();

        const float e0 = bufEA[p][rb + 0], e1 = bufEA[p][rb + 1],
                    e2 = bufEA[p][rb + 2], e3 = bufEA[p][rb + 3],
                    e4 = bufEA[p][rb + 4], e5 = bufEA[p][rb + 5],
                    e6 = bufEA[p][rb + 6];
        const float s = ((e0 + e1) + (e2 + e3)) + ((e4 + e5) + e6);

        // Speculative fast-path L; ballot resolves in parallel, rescue
        // overwrites. Same values as R7 (pure scheduling change).
        float L = log2_hw(s);
        const bool ok = (s >= LOF) && (s <= HIF);   // NaN/inf -> false
        if (__ballot(ok) != ~0ull) {                // identical in all waves
            const float a0 = bufAA[p][rb + 0], a1 = bufAA[p][rb + 1],
                        a2 = bufAA[p][rb + 2], a3 = bufAA[p][rb + 3],
                        a4 = bufAA[p][rb + 4], a5 = bufAA[p][rb + 5],
                        a6 = bufAA[p][rb + 6];
            const float m = fmaxf(fmaxf(fmaxf(a0, a1), fmaxf(a2, a3)),
                                  fmaxf(fmaxf(a4, a5), a6));
            const float s2 = ((exp2_hw(a0 - m) + exp2_hw(a1 - m))
                            + (exp2_hw(a2 - m) + exp2_hw(a3 - m)))
                           + ((exp2_hw(a4 - m) + exp2_hw(a5 - m))
                            + exp2_hw(a6 - m));
            L = m + log2_hw(s2);
        }

        const float q = t - L;
        const float e = exp2_hw(q);
        const float ss = wave_sum_bcast(e);         // wave-uniform (SGPR)

        // Speculative fast-path L2; uint window check on the SGPR value
        // (equivalent to float check for >=0 sums; NaN/inf/0 -> rescue).
        float L2 = log2_hw(ss);
        const unsigned ssu = __float_as_uint(ss);
        if (ssu < LOu || ssu > HIu) {               // wave-local decision
            const float M   = wave_max_bcast(q);
            const float e2  = exp2_hw(q - M);
            const float ss2 = wave_sum_bcast(e2);   // in [1,64]
            L2 = M + log2_hw(ss2);
        }
        t = q - L2;
    }

    // ---- Switch @120 (R13-validated mechanics): U = 2^t, underflow->0. ----
    float U = exp2_hw(t);
    const float Bj = exp2_hw(cbj);

    // ---- Phase 2: multiplicative, transposed. 1 barrier/iter. ----
    for (int it2 = 0; it2 < ITERS2_; ++it2) {
        const int p = it2 & 1;
        bufEA[p][base] = U * Bj;
        __syncthreads();
        const float p0 = bufEA[p][rb + 0], p1 = bufEA[p][rb + 1],
                    p2 = bufEA[p][rb + 2], p3 = bufEA[p][rb + 3],
                    p4 = bufEA[p][rb + 4], p5 = bufEA[p][rb + 5],
                    p6 = bufEA[p][rb + 6];
        const float s  = ((p0 + p1) + (p2 + p3)) + ((p4 + p5) + p6);
        const float rs = rcp_hw(s);
        const float w  = U * rs;
        const float ss = wave_sum_bcast(w);
        U = w * rcp_hw(ss);
    }

    // ---- Epilogue: P = U*bT; normalize by total (+TINY). ----
    const float pr = U * bTj;
    const float cs = wave_sum_bcast(pr);   // column sum (wave-uniform)
    if (lane == 0) ldsS[wid] = cs;
    __syncthreads();
    const float total = ((ldsS[0] + ldsS[1]) + (ldsS[2] + ldsS[3]))
                      + ((ldsS[4] + ldsS[5]) + ldsS[6]);
    out[lane * NB + wid] = pr * (1.0f / (total + TINY_));
}

extern "C" void kernel_launch(void* const* d_in, const int* in_sizes, int n_in,
                              void* d_out, int out_size, void* d_ws, size_t ws_size,
                              hipStream_t stream) {
    const float* theta = (const float*)d_in[0];
    const float* phi   = (const float*)d_in[1];
    const float* n     = (const float*)d_in[2];
    const float* sens  = (const float*)d_in[3];
    const float* err   = (const float*)d_in[4];
    float* out = (float*)d_out;

    sinkhorn_kernel<<<1, 448, 0, stream>>>(theta, phi, n, sens, err, out);
}